// Round 8
// baseline (897.928 us; speedup 1.0000x reference)
//
#include <hip/hip_runtime.h>

#define BB 32
#define NN 128
#define EE 16384
#define ROWS_E (BB*EE)     // 524288
#define ROWS_N (BB*NN)     // 4096
#define EPS_BN 1e-5f

// d_out layout (floats): h_out, x_out, m
#define XOUT_OFF (ROWS_N*72)
#define M_OFF    (XOUT_OFF + ROWS_N*4)

// ws layout (floats)
#define ST1_OFF 0
#define ST2_OFF 512
#define AGG_OFF 1024
#define CNT_OFF (AGG_OFF + ROWS_N*4)
#define MAGG_OFF (CNT_OFF + ROWS_N)       // 21504
#define Z2_OFF (MAGG_OFF + ROWS_N*72)     // 316416
#define WB_OFF (Z2_OFF + ROWS_N*72)       // 611328 floats; ushort region after
// ab scratch [4096][144] fp32 = 589824 floats: occupies magg+z2 regions exactly
// (consumed by the edge kernels before magg/z2 are written)

// transposed bf16 weight buffer in ws (ushort offsets)
#define WE1T_OFF 0          // [80][168] (kept for layout stability; unused now)
#define WE2T_OFF 13440      // [80][104]
#define WX1T_OFF 21760      // [80][104]
#define WH1T_OFF 30080      // [80][168]
#define WH2T_OFF 43520      // [80][104]
#define WB_TOTAL 51840
// Wab^T [144][96] bf16 lives in the xout region of d_out (written only at the end)
#define WAB_TOTAL 13824
#define PREP_TOTAL (WB_TOTAL + WAB_TOTAL)

typedef __attribute__((ext_vector_type(8))) short short8;
typedef __attribute__((ext_vector_type(4))) float f32x4;

__device__ __forceinline__ float psi_f(float p) {
    return copysignf(log1pf(fabsf(p)), p);
}
// hardware bf16 pack: D = {lo: bf16(a), hi: bf16(b)} (RNE), 1 VALU
__device__ __forceinline__ unsigned pk(float a, float b) {
    unsigned r;
    asm("v_cvt_pk_bf16_f32 %0, %1, %2" : "=v"(r) : "v"(a), "v"(b));
    return r;
}
__device__ __forceinline__ unsigned short f2bf(float f) {
    unsigned r;
    asm("v_cvt_pk_bf16_f32 %0, %1, %1" : "=v"(r) : "v"(f));
    return (unsigned short)r;
}

// ---------- weight prep: transpose + bf16, pad with zeros; Wab^T to d_out xout region
__global__ void k_prep(const float* __restrict__ We1, const float* __restrict__ We2,
                       const float* __restrict__ Wx1, const float* __restrict__ Wh1,
                       const float* __restrict__ Wh2, unsigned short* __restrict__ wb,
                       unsigned short* __restrict__ wab)
{
    int idx = blockIdx.x * 256 + threadIdx.x;
    if (idx >= PREP_TOTAL) return;
    if (idx >= WB_TOTAL) {
        // Wab^T[n][k]: n=0..143 output channel (a:0-71 uses We1 rows 0..71,
        // b:72-143 uses rows 72..143), k=0..95 input dim (h), zero-pad k>=72
        int off = idx - WB_TOTAL, n = off / 96, k = off % 96;
        float v = 0.f;
        if (k < 72) v = (n < 72) ? We1[k * 72 + n] : We1[(72 + k) * 72 + (n - 72)];
        wab[off] = f2bf(v);
        return;
    }
    const float* src; int off, n, k, K;
    if (idx < WE2T_OFF)      { off = idx;            n = off/168; k = off%168; src = We1; K = 146; }
    else if (idx < WH1T_OFF && idx >= WX1T_OFF) { off = idx - WX1T_OFF; n = off/104; k = off%104; src = Wx1; K = 72; }
    else if (idx < WX1T_OFF) { off = idx - WE2T_OFF; n = off/104; k = off%104; src = We2; K = 72; }
    else if (idx < WH2T_OFF) { off = idx - WH1T_OFF; n = off/168; k = off%168; src = Wh1; K = 148; }
    else                     { off = idx - WH2T_OFF; n = off/104; k = off%104; src = Wh2; K = 72; }
    float v = (n < 72 && k < K) ? src[k * 72 + n] : 0.f;
    wb[idx] = f2bf(v);
}

// ---------- k_ab: a|b = h @ Wab  (4096 rows x 144 cols, K=72 pad 96) -> fp32 ab
__global__ __launch_bounds__(256, 2) void k_ab(
    const float* __restrict__ h, const unsigned short* __restrict__ Wabt,
    float* __restrict__ ab)
{
    __shared__ unsigned short Hs[128 * 104];
    int tid = threadIdx.x;
    int rl = tid >> 1, half = tid & 1;
    size_t row = (size_t)blockIdx.x * 128 + rl;
    const float4* hp = (const float4*)(h + row * 72) + half * 9;
    uint2* hr = (uint2*)(&Hs[rl * 104 + half * 36]);
    #pragma unroll
    for (int q = 0; q < 9; q++) {
        float4 v = hp[q];
        hr[q] = make_uint2(pk(v.x, v.y), pk(v.z, v.w));
    }
    {   // zero cols 72..95
        uint2* zp = (uint2*)(&Hs[rl * 104 + 72 + half * 12]);
        zp[0] = make_uint2(0u, 0u); zp[1] = make_uint2(0u, 0u); zp[2] = make_uint2(0u, 0u);
    }
    // no barrier: per-wave row ownership (rl = tid>>1 spans wv*32..+31)
    int wv = tid >> 6, lane = tid & 63, c = lane & 15, quad = lane >> 4;
    f32x4 acc[2][9] = {};
    #pragma unroll
    for (int kc = 0; kc < 3; kc++) {
        int k0 = kc * 32 + quad * 8;
        short8 a0 = *(const short8*)(&Hs[(wv * 32 + c) * 104 + k0]);
        short8 a1 = *(const short8*)(&Hs[(wv * 32 + 16 + c) * 104 + k0]);
        #pragma unroll
        for (int ct = 0; ct < 9; ct++) {
            short8 bf = *(const short8*)(&Wabt[(ct * 16 + c) * 96 + k0]);
            acc[0][ct] = __builtin_amdgcn_mfma_f32_16x16x32_bf16(a0, bf, acc[0][ct], 0, 0, 0);
            acc[1][ct] = __builtin_amdgcn_mfma_f32_16x16x32_bf16(a1, bf, acc[1][ct], 0, 0, 0);
        }
    }
    size_t rbase = (size_t)blockIdx.x * 128 + wv * 32 + quad * 4;
    #pragma unroll
    for (int rt = 0; rt < 2; rt++)
        #pragma unroll
        for (int ct = 0; ct < 9; ct++) {
            int col = ct * 16 + c;
            #pragma unroll
            for (int r = 0; r < 4; r++)
                ab[(rbase + rt * 16 + r) * 144 + col] = acc[rt][ct][r];
        }
}

// ---------- stats: z1[e,c] = a[i,c]+b[j,c]+u*alpha_c+t*beta_c ; per-channel sum/sumsq
__global__ void k_stats_lite(
    const float* __restrict__ ab, const float* __restrict__ x,
    const int* __restrict__ ei, const int* __restrict__ ej,
    const float* __restrict__ We1, float* __restrict__ st)
{
    __shared__ float ssum[4][72];
    __shared__ float ssq[4][72];
    int c = threadIdx.x, ty = threadIdx.y;
    float al = We1[144 * 72 + c], be = We1[145 * 72 + c];
    float s = 0.f, q = 0.f;
    for (int e = blockIdx.x * 4 + ty; e < ROWS_E; e += 4096) {
        int b = e >> 14;
        int i = ei[e], j = ej[e];
        float4 xi = *(const float4*)(x + (size_t)(b * 128 + i) * 4);
        float4 xj = *(const float4*)(x + (size_t)(b * 128 + j) * 4);
        float d0 = xi.x - xj.x, d1 = xi.y - xj.y, d2 = xi.z - xj.z, d3 = xi.w - xj.w;
        float u = psi_f(d0*d0 - d1*d1 - d2*d2 - d3*d3);
        float t = psi_f(xi.x*xj.x - xi.y*xj.y - xi.z*xj.z - xi.w*xj.w);
        float av = ab[(size_t)(b * 128 + i) * 144 + c];
        float bv = ab[(size_t)(b * 128 + j) * 144 + 72 + c];
        float z = av + bv + u * al + t * be;
        s += z; q += z * z;
    }
    ssum[ty][c] = s; ssq[ty][c] = q;
    __syncthreads();
    if (ty == 0) {
        s = ssum[0][c] + ssum[1][c] + ssum[2][c] + ssum[3][c];
        q = ssq[0][c] + ssq[1][c] + ssq[2][c] + ssq[3][c];
        atomicAdd(&st[c], s);
        atomicAdd(&st[72 + c], q);
    }
}

// fold BN1: st[144+c] = iv*g1 (scale), st[216+c] = b1 - mean*iv*g1 (shift)
__global__ void k_finalize1(float* __restrict__ st, const float* __restrict__ g1,
                            const float* __restrict__ b1, float inv_rows)
{
    int c = threadIdx.x;
    if (c < 72) {
        float mean = st[c] * inv_rows;
        float var  = st[72 + c] * inv_rows - mean * mean;
        float sc = rsqrtf(var + EPS_BN) * g1[c];
        st[144 + c] = sc;
        st[216 + c] = b1[c] - mean * sc;
    }
}

__global__ void k_finalize(float* __restrict__ st, float inv_rows)
{
    int c = threadIdx.x;
    if (c < 72) {
        float mean = st[c] * inv_rows;
        float var  = st[72 + c] * inv_rows - mean * mean;
        st[144 + c] = mean;
        st[216 + c] = rsqrtf(var + EPS_BN);
    }
}

// ---------- edge fused: gather a,b -> z1 -> BN+ReLU (folded) -> bf16 LDS -> GEMM2
//            -> gate -> m ; GEMM3 -> g2 -> scatter agg/cnt.  No GEMM1, no z1 memory.
__global__ __launch_bounds__(256, 4) void k_edge_fused(
    const float* __restrict__ ab, const float* __restrict__ x,
    const int* __restrict__ ei, const int* __restrict__ ej,
    const float* __restrict__ We1, const float* __restrict__ st1,
    const float* __restrict__ be2, const float* __restrict__ Wm, const float* __restrict__ bm,
    const float* __restrict__ bx1, const float* __restrict__ Wx2,
    const unsigned short* __restrict__ We2t, const unsigned short* __restrict__ Wx1t,
    float* __restrict__ m, float* __restrict__ agg, float* __restrict__ cnt)
{
    __shared__ unsigned short Zt[128 * 104];
    __shared__ float g2buf[128];
    int tid = threadIdx.x;
    int rl = tid >> 1, half = tid & 1;
    size_t row = (size_t)blockIdx.x * 128 + rl;
    int b = (int)(row >> 14);
    int i = ei[row], j = ej[row];
    float4 xi = *(const float4*)(x + (size_t)(b * 128 + i) * 4);
    float4 xj = *(const float4*)(x + (size_t)(b * 128 + j) * 4);
    float d0 = xi.x - xj.x, d1 = xi.y - xj.y, d2 = xi.z - xj.z, d3 = xi.w - xj.w;
    float u = psi_f(d0*d0 - d1*d1 - d2*d2 - d3*d3);
    float t = psi_f(xi.x*xj.x - xi.y*xj.y - xi.z*xj.z - xi.w*xj.w);
    const float4* ar  = (const float4*)(ab + (size_t)(b * 128 + i) * 144 + half * 36);
    const float4* br  = (const float4*)(ab + (size_t)(b * 128 + j) * 144 + 72 + half * 36);
    const float4* alp = (const float4*)(We1 + 144 * 72 + half * 36);
    const float4* bep = (const float4*)(We1 + 145 * 72 + half * 36);
    const float4* scp = (const float4*)(st1 + 144 + half * 36);
    const float4* shp = (const float4*)(st1 + 216 + half * 36);
    uint2* zrow = (uint2*)(&Zt[rl * 104 + half * 36]);
    #pragma unroll
    for (int q = 0; q < 9; q++) {
        float4 av = ar[q], bv = br[q], al = alp[q], be = bep[q], sc = scp[q], sh = shp[q];
        float z0 = fmaxf((av.x + bv.x + u * al.x + t * be.x) * sc.x + sh.x, 0.f);
        float z1 = fmaxf((av.y + bv.y + u * al.y + t * be.y) * sc.y + sh.y, 0.f);
        float z2 = fmaxf((av.z + bv.z + u * al.z + t * be.z) * sc.z + sh.z, 0.f);
        float z3 = fmaxf((av.w + bv.w + u * al.w + t * be.w) * sc.w + sh.w, 0.f);
        zrow[q] = make_uint2(pk(z0, z1), pk(z2, z3));
    }
    {   // zero cols 72..95 (GEMM2/3 read k < 96)
        uint2* zp = (uint2*)(&Zt[rl * 104 + 72 + half * 12]);
        zp[0] = make_uint2(0u, 0u); zp[1] = make_uint2(0u, 0u); zp[2] = make_uint2(0u, 0u);
    }
    // no barrier: per-wave row ownership

    int wv = tid >> 6, lane = tid & 63, c = lane & 15, quad = lane >> 4;
    // GEMM2 (B from global, L1/L2-hit)
    f32x4 acc2[2][5] = {};
    #pragma unroll
    for (int kc = 0; kc < 3; kc++) {
        int k0 = kc * 32 + quad * 8;
        short8 a0 = *(const short8*)(&Zt[(wv * 32 + c) * 104 + k0]);
        short8 a1 = *(const short8*)(&Zt[(wv * 32 + 16 + c) * 104 + k0]);
        #pragma unroll
        for (int ct = 0; ct < 5; ct++) {
            short8 bf = *(const short8*)(&We2t[(ct * 16 + c) * 104 + k0]);
            acc2[0][ct] = __builtin_amdgcn_mfma_f32_16x16x32_bf16(a0, bf, acc2[0][ct], 0, 0, 0);
            acc2[1][ct] = __builtin_amdgcn_mfma_f32_16x16x32_bf16(a1, bf, acc2[1][ct], 0, 0, 0);
        }
    }
    // epilogue: tmv = relu(acc+be2); gate s = sum tmv*Wm
    float part[2][4] = {};
    float bm0 = bm[0];
    #pragma unroll
    for (int ct = 0; ct < 5; ct++) {
        int col = ct * 16 + c;
        float bias = (col < 72) ? be2[col] : 0.f;
        float wm   = (col < 72) ? Wm[col]  : 0.f;
        #pragma unroll
        for (int rt = 0; rt < 2; rt++)
            #pragma unroll
            for (int r = 0; r < 4; r++) {
                float tv = fmaxf(acc2[rt][ct][r] + bias, 0.f);
                acc2[rt][ct][r] = tv;
                part[rt][r] += tv * wm;
            }
    }
    float sg[2][4];
    #pragma unroll
    for (int rt = 0; rt < 2; rt++)
        #pragma unroll
        for (int r = 0; r < 4; r++) {
            float s = part[rt][r];
            s += __shfl_xor(s, 1); s += __shfl_xor(s, 2);
            s += __shfl_xor(s, 4); s += __shfl_xor(s, 8);
            sg[rt][r] = 1.f / (1.f + expf(-(s + bm0)));
        }
    // m = t * gate: write global fp32 + bf16 back to own slab (cols 0..79)
    size_t rbase = (size_t)blockIdx.x * 128 + wv * 32 + quad * 4;
    #pragma unroll
    for (int rt = 0; rt < 2; rt++)
        #pragma unroll
        for (int ct = 0; ct < 5; ct++) {
            int col = ct * 16 + c;
            #pragma unroll
            for (int r = 0; r < 4; r++) {
                float mv = acc2[rt][ct][r] * sg[rt][r];
                int lrow = wv * 32 + rt * 16 + quad * 4 + r;
                Zt[lrow * 104 + col] = f2bf(mv);
                if (col < 72) m[(rbase + rt * 16 + r) * 72 + col] = mv;
            }
        }
    // GEMM3: u = m @ Wx1 (same wave's rows)
    f32x4 acc3[2][5] = {};
    #pragma unroll
    for (int kc = 0; kc < 3; kc++) {
        int k0 = kc * 32 + quad * 8;
        short8 a0 = *(const short8*)(&Zt[(wv * 32 + c) * 104 + k0]);
        short8 a1 = *(const short8*)(&Zt[(wv * 32 + 16 + c) * 104 + k0]);
        #pragma unroll
        for (int ct = 0; ct < 5; ct++) {
            short8 bf = *(const short8*)(&Wx1t[(ct * 16 + c) * 104 + k0]);
            acc3[0][ct] = __builtin_amdgcn_mfma_f32_16x16x32_bf16(a0, bf, acc3[0][ct], 0, 0, 0);
            acc3[1][ct] = __builtin_amdgcn_mfma_f32_16x16x32_bf16(a1, bf, acc3[1][ct], 0, 0, 0);
        }
    }
    float part3[2][4] = {};
    #pragma unroll
    for (int ct = 0; ct < 5; ct++) {
        int col = ct * 16 + c;
        float bias = (col < 72) ? bx1[col] : 0.f;
        float wx   = (col < 72) ? Wx2[col] : 0.f;
        #pragma unroll
        for (int rt = 0; rt < 2; rt++)
            #pragma unroll
            for (int r = 0; r < 4; r++)
                part3[rt][r] += fmaxf(acc3[rt][ct][r] + bias, 0.f) * wx;
    }
    #pragma unroll
    for (int rt = 0; rt < 2; rt++)
        #pragma unroll
        for (int r = 0; r < 4; r++) {
            float s = part3[rt][r];
            s += __shfl_xor(s, 1); s += __shfl_xor(s, 2);
            s += __shfl_xor(s, 4); s += __shfl_xor(s, 8);
            if (c == 0) g2buf[wv * 32 + rt * 16 + quad * 4 + r] = s;
        }
    __syncthreads();
    // scatter agg/cnt
    if (tid < 128) {
        size_t erow = (size_t)blockIdx.x * 128 + tid;
        int b2 = (int)(erow >> 14);
        int i2 = ei[erow], j2 = ej[erow];
        float g2 = g2buf[tid];
        float4 xi2 = *(const float4*)(x + (size_t)(b2 * 128 + i2) * 4);
        float4 xj2 = *(const float4*)(x + (size_t)(b2 * 128 + j2) * 4);
        float t0 = fminf(fmaxf((xi2.x - xj2.x) * g2, -100.f), 100.f);
        float t1 = fminf(fmaxf((xi2.y - xj2.y) * g2, -100.f), 100.f);
        float t2 = fminf(fmaxf((xi2.z - xj2.z) * g2, -100.f), 100.f);
        float t3 = fminf(fmaxf((xi2.w - xj2.w) * g2, -100.f), 100.f);
        float* ap = agg + (size_t)(b2 * 128 + i2) * 4;
        atomicAdd(ap + 0, t0); atomicAdd(ap + 1, t1);
        atomicAdd(ap + 2, t2); atomicAdd(ap + 3, t3);
        atomicAdd(cnt + (size_t)(b2 * 128 + i2), 1.f);
    }
}

// ---------- magg: segment-sum of m over edges, LDS-staged (1024 blocks, 512 edges each)
__global__ __launch_bounds__(256, 4) void k_magg(
    const float* __restrict__ m, const int* __restrict__ ei, float* __restrict__ magg)
{
    __shared__ float accum[128 * 72];
    int tid = threadIdx.x;
    for (int q = tid; q < 9216; q += 256) accum[q] = 0.f;
    __syncthreads();
    int b = blockIdx.x >> 5, chunk = blockIdx.x & 31;
    int wv = tid >> 6, lane = tid & 63;
    int ebase = b * 16384 + chunk * 512;
    for (int e = wv; e < 512; e += 8) {
        int e0 = ebase + e, e1 = ebase + e + 4;
        int n0 = ei[e0], n1 = ei[e1];
        const float* r0 = m + (size_t)e0 * 72;
        const float* r1 = m + (size_t)e1 * 72;
        float v0 = r0[lane];
        float v1 = r1[lane];
        float t0 = (lane < 8) ? r0[64 + lane] : 0.f;
        float t1 = (lane < 8) ? r1[64 + lane] : 0.f;
        atomicAdd(&accum[n0 * 72 + lane], v0);
        if (lane < 8) atomicAdd(&accum[n0 * 72 + 64 + lane], t0);
        atomicAdd(&accum[n1 * 72 + lane], v1);
        if (lane < 8) atomicAdd(&accum[n1 * 72 + 64 + lane], t1);
    }
    __syncthreads();
    float* mg = magg + (size_t)b * 9216;
    for (int q = tid; q < 9216; q += 256) atomicAdd(&mg[q], accum[q]);
}

// ---------- node GEMM1: z2 = [h, magg, node_attr] @ Wh1 + bh1 ; BN stats fused
__global__ __launch_bounds__(256) void k_node_gemm1(
    const float* __restrict__ h, const float* __restrict__ node_attr,
    const float* __restrict__ magg, const unsigned short* __restrict__ Wh1t,
    const float* __restrict__ bh1, float* __restrict__ z2, float* __restrict__ st)
{
    __shared__ unsigned short At[128 * 168];
    __shared__ unsigned short Wt[80 * 168];
    __shared__ float sred[4][144];
    int tid = threadIdx.x;
    {
        const uint4* s = (const uint4*)Wh1t; uint4* d = (uint4*)Wt;
        for (int q = tid; q < 1680; q += 256) d[q] = s[q];
    }
    int rl = tid >> 1, half = tid & 1;
    size_t row = (size_t)blockIdx.x * 128 + rl;
    const float4* sp = (const float4*)((half ? magg : h) + row * 72);
    uint2* arow = (uint2*)(&At[rl * 168 + half * 72]);
    #pragma unroll
    for (int q = 0; q < 18; q++) {
        float4 v = sp[q];
        arow[q] = make_uint2(pk(v.x, v.y), pk(v.z, v.w));
    }
    if (half) {
        float4 na = *(const float4*)(node_attr + row * 4);
        *(unsigned*)(&At[rl * 168 + 144]) = pk(na.x, na.y);
        *(unsigned*)(&At[rl * 168 + 146]) = pk(na.z, na.w);
        unsigned* tailp = (unsigned*)(&At[rl * 168 + 148]);
        #pragma unroll
        for (int q = 0; q < 10; q++) tailp[q] = 0u;
    }
    __syncthreads();

    int wv = tid >> 6, lane = tid & 63, c = lane & 15, quad = lane >> 4;
    f32x4 acc[2][5] = {};
    #pragma unroll
    for (int kc = 0; kc < 5; kc++) {
        int k0 = kc * 32 + quad * 8;
        short8 a0 = *(const short8*)(&At[(wv * 32 + c) * 168 + k0]);
        short8 a1 = *(const short8*)(&At[(wv * 32 + 16 + c) * 168 + k0]);
        #pragma unroll
        for (int ct = 0; ct < 5; ct++) {
            short8 bf = *(const short8*)(&Wt[(ct * 16 + c) * 168 + k0]);
            acc[0][ct] = __builtin_amdgcn_mfma_f32_16x16x32_bf16(a0, bf, acc[0][ct], 0, 0, 0);
            acc[1][ct] = __builtin_amdgcn_mfma_f32_16x16x32_bf16(a1, bf, acc[1][ct], 0, 0, 0);
        }
    }
    size_t rbase = (size_t)blockIdx.x * 128 + wv * 32 + quad * 4;
    #pragma unroll
    for (int ct = 0; ct < 5; ct++) {
        int col = ct * 16 + c;
        float bias = (col < 72) ? bh1[col] : 0.f;
        float s = 0.f, q = 0.f;
        #pragma unroll
        for (int rt = 0; rt < 2; rt++) {
            float* op = z2 + (rbase + rt * 16) * 72 + col;
            #pragma unroll
            for (int r = 0; r < 4; r++) {
                float v = acc[rt][ct][r] + bias;
                if (col < 72) op[(size_t)r * 72] = v;
                s += v; q += v * v;
            }
        }
        s += __shfl_xor(s, 16); s += __shfl_xor(s, 32);
        q += __shfl_xor(q, 16); q += __shfl_xor(q, 32);
        if (lane < 16 && col < 72) { sred[wv][col] = s; sred[wv][72 + col] = q; }
    }
    __syncthreads();
    if (tid < 144)
        atomicAdd(&st[tid], sred[0][tid] + sred[1][tid] + sred[2][tid] + sred[3][tid]);
}

// ---------- node final: BN2+ReLU -> MFMA @Wh2 + bh2 + h ; x_out
__global__ __launch_bounds__(256) void k_node_final(
    const float* __restrict__ h, const float* __restrict__ x,
    const float* __restrict__ z2, const float* __restrict__ st2,
    const float* __restrict__ gh, const float* __restrict__ bh,
    const unsigned short* __restrict__ Wh2t, const float* __restrict__ bh2,
    const float* __restrict__ agg, const float* __restrict__ cnt,
    float* __restrict__ hout, float* __restrict__ xout)
{
    __shared__ unsigned short Zt[128 * 104];
    __shared__ unsigned short Wt[80 * 104];
    int tid = threadIdx.x;
    {
        const uint4* s = (const uint4*)Wh2t; uint4* d = (uint4*)Wt;
        for (int q = tid; q < 1040; q += 256) d[q] = s[q];
    }
    int rl = tid >> 1, half = tid & 1;
    size_t row = (size_t)blockIdx.x * 128 + rl;
    const float* mean = st2 + 144;
    const float* inv  = st2 + 216;
    const float4* zp = (const float4*)(z2 + row * 72) + half * 9;
    uint2* arow = (uint2*)(&Zt[rl * 104 + half * 36]);
    #pragma unroll
    for (int q = 0; q < 9; q++) {
        int k = half * 36 + q * 4;
        float4 v = zp[q];
        float a0 = fmaxf((v.x - mean[k  ]) * inv[k  ] * gh[k  ] + bh[k  ], 0.f);
        float a1 = fmaxf((v.y - mean[k+1]) * inv[k+1] * gh[k+1] + bh[k+1], 0.f);
        float a2 = fmaxf((v.z - mean[k+2]) * inv[k+2] * gh[k+2] + bh[k+2], 0.f);
        float a3 = fmaxf((v.w - mean[k+3]) * inv[k+3] * gh[k+3] + bh[k+3], 0.f);
        arow[q] = make_uint2(pk(a0, a1), pk(a2, a3));
    }
    uint2* prow = (uint2*)(&Zt[rl * 104]);
    #pragma unroll
    for (int q = 0; q < 4; q++) prow[18 + half * 4 + q] = make_uint2(0u, 0u);
    __syncthreads();

    int wv = tid >> 6, lane = tid & 63, c = lane & 15, quad = lane >> 4;
    f32x4 acc[2][5] = {};
    #pragma unroll
    for (int kc = 0; kc < 3; kc++) {
        int k0 = kc * 32 + quad * 8;
        short8 a0 = *(const short8*)(&Zt[(wv * 32 + c) * 104 + k0]);
        short8 a1 = *(const short8*)(&Zt[(wv * 32 + 16 + c) * 104 + k0]);
        #pragma unroll
        for (int ct = 0; ct < 5; ct++) {
            short8 bf = *(const short8*)(&Wt[(ct * 16 + c) * 104 + k0]);
            acc[0][ct] = __builtin_amdgcn_mfma_f32_16x16x32_bf16(a0, bf, acc[0][ct], 0, 0, 0);
            acc[1][ct] = __builtin_amdgcn_mfma_f32_16x16x32_bf16(a1, bf, acc[1][ct], 0, 0, 0);
        }
    }
    size_t rbase = (size_t)blockIdx.x * 128 + wv * 32 + quad * 4;
    #pragma unroll
    for (int rt = 0; rt < 2; rt++)
        #pragma unroll
        for (int ct = 0; ct < 5; ct++) {
            int col = ct * 16 + c;
            if (col < 72) {
                float bias = bh2[col];
                #pragma unroll
                for (int r = 0; r < 4; r++) {
                    size_t gr = (rbase + rt * 16 + r);
                    hout[gr * 72 + col] = h[gr * 72 + col] + acc[rt][ct][r] + bias;
                }
            }
        }
    if (tid < 128) {
        size_t nrow = (size_t)blockIdx.x * 128 + tid;
        float cn = fmaxf(cnt[nrow], 1.f);
        float4 ag = *(const float4*)(agg + nrow * 4);
        float4 xv = *(const float4*)(x + nrow * 4);
        ((float4*)xout)[nrow] = make_float4(xv.x + ag.x / cn, xv.y + ag.y / cn,
                                            xv.z + ag.z / cn, xv.w + ag.w / cn);
    }
}

extern "C" void kernel_launch(void* const* d_in, const int* in_sizes, int n_in,
                              void* d_out, int out_size, void* d_ws, size_t ws_size,
                              hipStream_t stream)
{
    const float* h   = (const float*)d_in[0];
    const float* x   = (const float*)d_in[1];
    const int*   ei  = (const int*)d_in[2];
    const int*   ej  = (const int*)d_in[3];
    const float* na  = (const float*)d_in[4];
    const float* We1 = (const float*)d_in[5];
    const float* g1  = (const float*)d_in[6];
    const float* b1  = (const float*)d_in[7];
    const float* We2 = (const float*)d_in[8];
    const float* be2 = (const float*)d_in[9];
    const float* Wm  = (const float*)d_in[10];
    const float* bm  = (const float*)d_in[11];
    const float* Wx1 = (const float*)d_in[12];
    const float* bx1 = (const float*)d_in[13];
    const float* Wx2 = (const float*)d_in[14];
    const float* Wh1 = (const float*)d_in[15];
    const float* bh1 = (const float*)d_in[16];
    const float* gh  = (const float*)d_in[17];
    const float* bhp = (const float*)d_in[18];
    const float* Wh2 = (const float*)d_in[19];
    const float* bh2 = (const float*)d_in[20];

    float* out  = (float*)d_out;
    float* hout = out;
    float* xout = out + XOUT_OFF;
    float* m    = out + M_OFF;
    float* ws   = (float*)d_ws;
    float* st1  = ws + ST1_OFF;
    float* st2  = ws + ST2_OFF;
    float* agg  = ws + AGG_OFF;
    float* cnt  = ws + CNT_OFF;
    float* magg = ws + MAGG_OFF;
    float* z2   = ws + Z2_OFF;
    unsigned short* wb = (unsigned short*)(ws + WB_OFF);
    // ab scratch overlays magg+z2 (consumed before they're written);
    // Wab^T overlays xout (written only by k_node_final at the very end)
    float* ab = ws + MAGG_OFF;
    unsigned short* wab = (unsigned short*)xout;

    hipMemsetAsync(d_ws, 0, (size_t)MAGG_OFF * sizeof(float), stream);
    k_prep<<<(PREP_TOTAL + 255) / 256, 256, 0, stream>>>(We1, We2, Wx1, Wh1, Wh2, wb, wab);
    k_ab<<<ROWS_N / 128, 256, 0, stream>>>(h, wab, ab);
    k_stats_lite<<<1024, dim3(72, 4), 0, stream>>>(ab, x, ei, ej, We1, st1);
    k_finalize1<<<1, 128, 0, stream>>>(st1, g1, b1, 1.0f / (float)ROWS_E);
    k_edge_fused<<<ROWS_E / 128, 256, 0, stream>>>(ab, x, ei, ej, We1, st1, be2, Wm, bm,
                                                   bx1, Wx2, wb + WE2T_OFF, wb + WX1T_OFF,
                                                   m, agg, cnt);
    hipMemsetAsync(magg, 0, (size_t)(ROWS_N * 72) * sizeof(float), stream);
    k_magg<<<1024, 256, 0, stream>>>(m, ei, magg);
    k_node_gemm1<<<ROWS_N / 128, 256, 0, stream>>>(h, na, magg, wb + WH1T_OFF, bh1, z2, st2);
    k_finalize<<<1, 128, 0, stream>>>(st2, 1.0f / (float)ROWS_N);
    k_node_final<<<ROWS_N / 128, 256, 0, stream>>>(h, x, z2, st2, gh, bhp,
                                                   wb + WH2T_OFF, bh2, agg, cnt, hout, xout);
}

// Round 9
// 638.571 us; speedup vs baseline: 1.4062x; 1.4062x over previous
//
#include <hip/hip_runtime.h>

#define BB 32
#define NN 128
#define EE 16384
#define ROWS_E (BB*EE)     // 524288
#define ROWS_N (BB*NN)     // 4096
#define EPS_BN 1e-5f

// d_out layout (floats): h_out, x_out, m
#define XOUT_OFF (ROWS_N*72)
#define M_OFF    (XOUT_OFF + ROWS_N*4)

// ws layout (floats)
#define ST1_OFF 0
#define ST2_OFF 512
#define AGG_OFF 1024
#define CNT_OFF (AGG_OFF + ROWS_N*4)
#define MAGG_OFF (CNT_OFF + ROWS_N)       // 21504
#define Z2_OFF (MAGG_OFF + ROWS_N*72)     // 316416
#define WB_OFF (Z2_OFF + ROWS_N*72)       // 611328 floats; ushort region after
// ab scratch [4096][144] fp32 = 589824 floats: occupies magg+z2 regions exactly
// (consumed by the edge kernels before magg/z2 are written)

// transposed bf16 weight buffer in ws (ushort offsets)
#define WE1T_OFF 0          // [80][168] (kept for layout stability; unused now)
#define WE2T_OFF 13440      // [80][104]
#define WX1T_OFF 21760      // [80][104]
#define WH1T_OFF 30080      // [80][168]
#define WH2T_OFF 43520      // [80][104]
#define WB_TOTAL 51840
// Wab^T [144][96] bf16 lives in the xout region of d_out (written only at the end)
#define WAB_TOTAL 13824
#define PREP_TOTAL (WB_TOTAL + WAB_TOTAL)

typedef __attribute__((ext_vector_type(8))) short short8;
typedef __attribute__((ext_vector_type(4))) float f32x4;

__device__ __forceinline__ float psi_f(float p) {
    return copysignf(log1pf(fabsf(p)), p);
}
// hardware bf16 pack: D = {lo: bf16(a), hi: bf16(b)} (RNE), 1 VALU
__device__ __forceinline__ unsigned pk(float a, float b) {
    unsigned r;
    asm("v_cvt_pk_bf16_f32 %0, %1, %2" : "=v"(r) : "v"(a), "v"(b));
    return r;
}
__device__ __forceinline__ unsigned short f2bf(float f) {
    unsigned r;
    asm("v_cvt_pk_bf16_f32 %0, %1, %1" : "=v"(r) : "v"(f));
    return (unsigned short)r;
}

// ---------- weight prep: transpose + bf16, pad with zeros; Wab^T to d_out xout region
__global__ void k_prep(const float* __restrict__ We1, const float* __restrict__ We2,
                       const float* __restrict__ Wx1, const float* __restrict__ Wh1,
                       const float* __restrict__ Wh2, unsigned short* __restrict__ wb,
                       unsigned short* __restrict__ wab)
{
    int idx = blockIdx.x * 256 + threadIdx.x;
    if (idx >= PREP_TOTAL) return;
    if (idx >= WB_TOTAL) {
        int off = idx - WB_TOTAL, n = off / 96, k = off % 96;
        float v = 0.f;
        if (k < 72) v = (n < 72) ? We1[k * 72 + n] : We1[(72 + k) * 72 + (n - 72)];
        wab[off] = f2bf(v);
        return;
    }
    const float* src; int off, n, k, K;
    if (idx < WE2T_OFF)      { off = idx;            n = off/168; k = off%168; src = We1; K = 146; }
    else if (idx < WH1T_OFF && idx >= WX1T_OFF) { off = idx - WX1T_OFF; n = off/104; k = off%104; src = Wx1; K = 72; }
    else if (idx < WX1T_OFF) { off = idx - WE2T_OFF; n = off/104; k = off%104; src = We2; K = 72; }
    else if (idx < WH2T_OFF) { off = idx - WH1T_OFF; n = off/168; k = off%168; src = Wh1; K = 148; }
    else                     { off = idx - WH2T_OFF; n = off/104; k = off%104; src = Wh2; K = 72; }
    float v = (n < 72 && k < K) ? src[k * 72 + n] : 0.f;
    wb[idx] = f2bf(v);
}

// ---------- k_ab: a|b = h @ Wab  (4096 rows x 144 cols, K=72 pad 96) -> fp32 ab
__global__ __launch_bounds__(256, 2) void k_ab(
    const float* __restrict__ h, const unsigned short* __restrict__ Wabt,
    float* __restrict__ ab)
{
    __shared__ unsigned short Hs[128 * 104];
    int tid = threadIdx.x;
    int rl = tid >> 1, half = tid & 1;
    size_t row = (size_t)blockIdx.x * 128 + rl;
    const float4* hp = (const float4*)(h + row * 72) + half * 9;
    uint2* hr = (uint2*)(&Hs[rl * 104 + half * 36]);
    #pragma unroll
    for (int q = 0; q < 9; q++) {
        float4 v = hp[q];
        hr[q] = make_uint2(pk(v.x, v.y), pk(v.z, v.w));
    }
    {   // zero cols 72..95
        uint2* zp = (uint2*)(&Hs[rl * 104 + 72 + half * 12]);
        zp[0] = make_uint2(0u, 0u); zp[1] = make_uint2(0u, 0u); zp[2] = make_uint2(0u, 0u);
    }
    // no barrier: per-wave row ownership (rl = tid>>1 spans wv*32..+31)
    int wv = tid >> 6, lane = tid & 63, c = lane & 15, quad = lane >> 4;
    f32x4 acc[2][9] = {};
    #pragma unroll
    for (int kc = 0; kc < 3; kc++) {
        int k0 = kc * 32 + quad * 8;
        short8 a0 = *(const short8*)(&Hs[(wv * 32 + c) * 104 + k0]);
        short8 a1 = *(const short8*)(&Hs[(wv * 32 + 16 + c) * 104 + k0]);
        #pragma unroll
        for (int ct = 0; ct < 9; ct++) {
            short8 bf = *(const short8*)(&Wabt[(ct * 16 + c) * 96 + k0]);
            acc[0][ct] = __builtin_amdgcn_mfma_f32_16x16x32_bf16(a0, bf, acc[0][ct], 0, 0, 0);
            acc[1][ct] = __builtin_amdgcn_mfma_f32_16x16x32_bf16(a1, bf, acc[1][ct], 0, 0, 0);
        }
    }
    size_t rbase = (size_t)blockIdx.x * 128 + wv * 32 + quad * 4;
    #pragma unroll
    for (int rt = 0; rt < 2; rt++)
        #pragma unroll
        for (int ct = 0; ct < 9; ct++) {
            int col = ct * 16 + c;
            #pragma unroll
            for (int r = 0; r < 4; r++)
                ab[(rbase + rt * 16 + r) * 144 + col] = acc[rt][ct][r];
        }
}

// ---------- stats v2: two-phase LDS tile. Phase A: 256 threads compute psi once per
// edge + int offsets -> LDS. Phase B: (72,4) channel sweep, 2 gathers + 4 VALU per
// (e,c). 1024 blocks x 2 tiles x 256 edges = 524288.
__global__ __launch_bounds__(288) void k_stats_lite(
    const float* __restrict__ ab, const float* __restrict__ x,
    const int* __restrict__ ei, const int* __restrict__ ej,
    const float* __restrict__ We1, float* __restrict__ st)
{
    __shared__ float uu[256], tt[256];
    __shared__ int iofs[256], jofs[256];
    __shared__ float ssum[4][72];
    __shared__ float ssq[4][72];
    int c = threadIdx.x, ty = threadIdx.y;
    int tf = ty * 72 + c;                 // flat tid 0..287
    float al = We1[144 * 72 + c], be = We1[145 * 72 + c];
    float s = 0.f, q = 0.f;
    int ebase = blockIdx.x * 512;
    #pragma unroll
    for (int tile = 0; tile < 2; tile++) {
        if (tf < 256) {
            int e = ebase + tile * 256 + tf;
            int b = e >> 14;
            int i = ei[e], j = ej[e];
            float4 xi = *(const float4*)(x + (size_t)(b * 128 + i) * 4);
            float4 xj = *(const float4*)(x + (size_t)(b * 128 + j) * 4);
            float d0 = xi.x - xj.x, d1 = xi.y - xj.y, d2 = xi.z - xj.z, d3 = xi.w - xj.w;
            uu[tf] = psi_f(d0*d0 - d1*d1 - d2*d2 - d3*d3);
            tt[tf] = psi_f(xi.x*xj.x - xi.y*xj.y - xi.z*xj.z - xi.w*xj.w);
            iofs[tf] = (b * 128 + i) * 144;
            jofs[tf] = (b * 128 + j) * 144 + 72;
        }
        __syncthreads();
        #pragma unroll 4
        for (int k = 0; k < 64; k++) {
            int idx = ty * 64 + k;
            float av = ab[iofs[idx] + c];
            float bv = ab[jofs[idx] + c];
            float z = (av + bv) + (uu[idx] * al + tt[idx] * be);
            s += z; q += z * z;
        }
        __syncthreads();
    }
    ssum[ty][c] = s; ssq[ty][c] = q;
    __syncthreads();
    if (ty == 0) {
        s = ssum[0][c] + ssum[1][c] + ssum[2][c] + ssum[3][c];
        q = ssq[0][c] + ssq[1][c] + ssq[2][c] + ssq[3][c];
        atomicAdd(&st[c], s);
        atomicAdd(&st[72 + c], q);
    }
}

// fold BN1: st[144+c] = iv*g1 (scale), st[216+c] = b1 - mean*iv*g1 (shift)
__global__ void k_finalize1(float* __restrict__ st, const float* __restrict__ g1,
                            const float* __restrict__ b1, float inv_rows)
{
    int c = threadIdx.x;
    if (c < 72) {
        float mean = st[c] * inv_rows;
        float var  = st[72 + c] * inv_rows - mean * mean;
        float sc = rsqrtf(var + EPS_BN) * g1[c];
        st[144 + c] = sc;
        st[216 + c] = b1[c] - mean * sc;
    }
}

__global__ void k_finalize(float* __restrict__ st, float inv_rows)
{
    int c = threadIdx.x;
    if (c < 72) {
        float mean = st[c] * inv_rows;
        float var  = st[72 + c] * inv_rows - mean * mean;
        st[144 + c] = mean;
        st[216 + c] = rsqrtf(var + EPS_BN);
    }
}

// ---------- edge fused: gather a,b -> z1 -> BN+ReLU (folded) -> bf16 LDS -> GEMM2
//            -> gate -> m ; GEMM3 -> g2 -> scatter agg/cnt.  No GEMM1, no z1 memory.
__global__ __launch_bounds__(256, 4) void k_edge_fused(
    const float* __restrict__ ab, const float* __restrict__ x,
    const int* __restrict__ ei, const int* __restrict__ ej,
    const float* __restrict__ We1, const float* __restrict__ st1,
    const float* __restrict__ be2, const float* __restrict__ Wm, const float* __restrict__ bm,
    const float* __restrict__ bx1, const float* __restrict__ Wx2,
    const unsigned short* __restrict__ We2t, const unsigned short* __restrict__ Wx1t,
    float* __restrict__ m, float* __restrict__ agg, float* __restrict__ cnt)
{
    __shared__ unsigned short Zt[128 * 104];
    __shared__ float g2buf[128];
    int tid = threadIdx.x;
    int rl = tid >> 1, half = tid & 1;
    size_t row = (size_t)blockIdx.x * 128 + rl;
    int b = (int)(row >> 14);
    int i = ei[row], j = ej[row];
    float4 xi = *(const float4*)(x + (size_t)(b * 128 + i) * 4);
    float4 xj = *(const float4*)(x + (size_t)(b * 128 + j) * 4);
    float d0 = xi.x - xj.x, d1 = xi.y - xj.y, d2 = xi.z - xj.z, d3 = xi.w - xj.w;
    float u = psi_f(d0*d0 - d1*d1 - d2*d2 - d3*d3);
    float t = psi_f(xi.x*xj.x - xi.y*xj.y - xi.z*xj.z - xi.w*xj.w);
    const float4* ar  = (const float4*)(ab + (size_t)(b * 128 + i) * 144 + half * 36);
    const float4* br  = (const float4*)(ab + (size_t)(b * 128 + j) * 144 + 72 + half * 36);
    const float4* alp = (const float4*)(We1 + 144 * 72 + half * 36);
    const float4* bep = (const float4*)(We1 + 145 * 72 + half * 36);
    const float4* scp = (const float4*)(st1 + 144 + half * 36);
    const float4* shp = (const float4*)(st1 + 216 + half * 36);
    uint2* zrow = (uint2*)(&Zt[rl * 104 + half * 36]);
    #pragma unroll
    for (int q = 0; q < 9; q++) {
        float4 av = ar[q], bv = br[q], al = alp[q], be = bep[q], sc = scp[q], sh = shp[q];
        float z0 = fmaxf((av.x + bv.x + u * al.x + t * be.x) * sc.x + sh.x, 0.f);
        float z1 = fmaxf((av.y + bv.y + u * al.y + t * be.y) * sc.y + sh.y, 0.f);
        float z2 = fmaxf((av.z + bv.z + u * al.z + t * be.z) * sc.z + sh.z, 0.f);
        float z3 = fmaxf((av.w + bv.w + u * al.w + t * be.w) * sc.w + sh.w, 0.f);
        zrow[q] = make_uint2(pk(z0, z1), pk(z2, z3));
    }
    {   // zero cols 72..95 (GEMM2/3 read k < 96)
        uint2* zp = (uint2*)(&Zt[rl * 104 + 72 + half * 12]);
        zp[0] = make_uint2(0u, 0u); zp[1] = make_uint2(0u, 0u); zp[2] = make_uint2(0u, 0u);
    }
    // no barrier: per-wave row ownership

    int wv = tid >> 6, lane = tid & 63, c = lane & 15, quad = lane >> 4;
    // GEMM2 (B from global, L1/L2-hit)
    f32x4 acc2[2][5] = {};
    #pragma unroll
    for (int kc = 0; kc < 3; kc++) {
        int k0 = kc * 32 + quad * 8;
        short8 a0 = *(const short8*)(&Zt[(wv * 32 + c) * 104 + k0]);
        short8 a1 = *(const short8*)(&Zt[(wv * 32 + 16 + c) * 104 + k0]);
        #pragma unroll
        for (int ct = 0; ct < 5; ct++) {
            short8 bf = *(const short8*)(&We2t[(ct * 16 + c) * 104 + k0]);
            acc2[0][ct] = __builtin_amdgcn_mfma_f32_16x16x32_bf16(a0, bf, acc2[0][ct], 0, 0, 0);
            acc2[1][ct] = __builtin_amdgcn_mfma_f32_16x16x32_bf16(a1, bf, acc2[1][ct], 0, 0, 0);
        }
    }
    // epilogue: tmv = relu(acc+be2); gate s = sum tmv*Wm
    float part[2][4] = {};
    float bm0 = bm[0];
    #pragma unroll
    for (int ct = 0; ct < 5; ct++) {
        int col = ct * 16 + c;
        float bias = (col < 72) ? be2[col] : 0.f;
        float wm   = (col < 72) ? Wm[col]  : 0.f;
        #pragma unroll
        for (int rt = 0; rt < 2; rt++)
            #pragma unroll
            for (int r = 0; r < 4; r++) {
                float tv = fmaxf(acc2[rt][ct][r] + bias, 0.f);
                acc2[rt][ct][r] = tv;
                part[rt][r] += tv * wm;
            }
    }
    float sg[2][4];
    #pragma unroll
    for (int rt = 0; rt < 2; rt++)
        #pragma unroll
        for (int r = 0; r < 4; r++) {
            float s = part[rt][r];
            s += __shfl_xor(s, 1); s += __shfl_xor(s, 2);
            s += __shfl_xor(s, 4); s += __shfl_xor(s, 8);
            sg[rt][r] = 1.f / (1.f + expf(-(s + bm0)));
        }
    // m = t * gate: write global fp32 + bf16 back to own slab (cols 0..79)
    size_t rbase = (size_t)blockIdx.x * 128 + wv * 32 + quad * 4;
    #pragma unroll
    for (int rt = 0; rt < 2; rt++)
        #pragma unroll
        for (int ct = 0; ct < 5; ct++) {
            int col = ct * 16 + c;
            #pragma unroll
            for (int r = 0; r < 4; r++) {
                float mv = acc2[rt][ct][r] * sg[rt][r];
                int lrow = wv * 32 + rt * 16 + quad * 4 + r;
                Zt[lrow * 104 + col] = f2bf(mv);
                if (col < 72) m[(rbase + rt * 16 + r) * 72 + col] = mv;
            }
        }
    // GEMM3: u = m @ Wx1 (same wave's rows)
    f32x4 acc3[2][5] = {};
    #pragma unroll
    for (int kc = 0; kc < 3; kc++) {
        int k0 = kc * 32 + quad * 8;
        short8 a0 = *(const short8*)(&Zt[(wv * 32 + c) * 104 + k0]);
        short8 a1 = *(const short8*)(&Zt[(wv * 32 + 16 + c) * 104 + k0]);
        #pragma unroll
        for (int ct = 0; ct < 5; ct++) {
            short8 bf = *(const short8*)(&Wx1t[(ct * 16 + c) * 104 + k0]);
            acc3[0][ct] = __builtin_amdgcn_mfma_f32_16x16x32_bf16(a0, bf, acc3[0][ct], 0, 0, 0);
            acc3[1][ct] = __builtin_amdgcn_mfma_f32_16x16x32_bf16(a1, bf, acc3[1][ct], 0, 0, 0);
        }
    }
    float part3[2][4] = {};
    #pragma unroll
    for (int ct = 0; ct < 5; ct++) {
        int col = ct * 16 + c;
        float bias = (col < 72) ? bx1[col] : 0.f;
        float wx   = (col < 72) ? Wx2[col] : 0.f;
        #pragma unroll
        for (int rt = 0; rt < 2; rt++)
            #pragma unroll
            for (int r = 0; r < 4; r++)
                part3[rt][r] += fmaxf(acc3[rt][ct][r] + bias, 0.f) * wx;
    }
    #pragma unroll
    for (int rt = 0; rt < 2; rt++)
        #pragma unroll
        for (int r = 0; r < 4; r++) {
            float s = part3[rt][r];
            s += __shfl_xor(s, 1); s += __shfl_xor(s, 2);
            s += __shfl_xor(s, 4); s += __shfl_xor(s, 8);
            if (c == 0) g2buf[wv * 32 + rt * 16 + quad * 4 + r] = s;
        }
    __syncthreads();
    // scatter agg/cnt
    if (tid < 128) {
        size_t erow = (size_t)blockIdx.x * 128 + tid;
        int b2 = (int)(erow >> 14);
        int i2 = ei[erow], j2 = ej[erow];
        float g2 = g2buf[tid];
        float4 xi2 = *(const float4*)(x + (size_t)(b2 * 128 + i2) * 4);
        float4 xj2 = *(const float4*)(x + (size_t)(b2 * 128 + j2) * 4);
        float t0 = fminf(fmaxf((xi2.x - xj2.x) * g2, -100.f), 100.f);
        float t1 = fminf(fmaxf((xi2.y - xj2.y) * g2, -100.f), 100.f);
        float t2 = fminf(fmaxf((xi2.z - xj2.z) * g2, -100.f), 100.f);
        float t3 = fminf(fmaxf((xi2.w - xj2.w) * g2, -100.f), 100.f);
        float* ap = agg + (size_t)(b2 * 128 + i2) * 4;
        atomicAdd(ap + 0, t0); atomicAdd(ap + 1, t1);
        atomicAdd(ap + 2, t2); atomicAdd(ap + 3, t3);
        atomicAdd(cnt + (size_t)(b2 * 128 + i2), 1.f);
    }
}

// ---------- magg: segment-sum of m over edges, LDS-staged (1024 blocks, 512 edges each)
__global__ __launch_bounds__(256, 4) void k_magg(
    const float* __restrict__ m, const int* __restrict__ ei, float* __restrict__ magg)
{
    __shared__ float accum[128 * 72];
    int tid = threadIdx.x;
    for (int q = tid; q < 9216; q += 256) accum[q] = 0.f;
    __syncthreads();
    int b = blockIdx.x >> 5, chunk = blockIdx.x & 31;
    int wv = tid >> 6, lane = tid & 63;
    int ebase = b * 16384 + chunk * 512;
    for (int e = wv; e < 512; e += 8) {
        int e0 = ebase + e, e1 = ebase + e + 4;
        int n0 = ei[e0], n1 = ei[e1];
        const float* r0 = m + (size_t)e0 * 72;
        const float* r1 = m + (size_t)e1 * 72;
        float v0 = r0[lane];
        float v1 = r1[lane];
        float t0 = (lane < 8) ? r0[64 + lane] : 0.f;
        float t1 = (lane < 8) ? r1[64 + lane] : 0.f;
        atomicAdd(&accum[n0 * 72 + lane], v0);
        if (lane < 8) atomicAdd(&accum[n0 * 72 + 64 + lane], t0);
        atomicAdd(&accum[n1 * 72 + lane], v1);
        if (lane < 8) atomicAdd(&accum[n1 * 72 + 64 + lane], t1);
    }
    __syncthreads();
    float* mg = magg + (size_t)b * 9216;
    for (int q = tid; q < 9216; q += 256) atomicAdd(&mg[q], accum[q]);
}

// ---------- node GEMM1: z2 = [h, magg, node_attr] @ Wh1 + bh1 ; BN stats fused
__global__ __launch_bounds__(256) void k_node_gemm1(
    const float* __restrict__ h, const float* __restrict__ node_attr,
    const float* __restrict__ magg, const unsigned short* __restrict__ Wh1t,
    const float* __restrict__ bh1, float* __restrict__ z2, float* __restrict__ st)
{
    __shared__ unsigned short At[128 * 168];
    __shared__ unsigned short Wt[80 * 168];
    __shared__ float sred[4][144];
    int tid = threadIdx.x;
    {
        const uint4* s = (const uint4*)Wh1t; uint4* d = (uint4*)Wt;
        for (int q = tid; q < 1680; q += 256) d[q] = s[q];
    }
    int rl = tid >> 1, half = tid & 1;
    size_t row = (size_t)blockIdx.x * 128 + rl;
    const float4* sp = (const float4*)((half ? magg : h) + row * 72);
    uint2* arow = (uint2*)(&At[rl * 168 + half * 72]);
    #pragma unroll
    for (int q = 0; q < 18; q++) {
        float4 v = sp[q];
        arow[q] = make_uint2(pk(v.x, v.y), pk(v.z, v.w));
    }
    if (half) {
        float4 na = *(const float4*)(node_attr + row * 4);
        *(unsigned*)(&At[rl * 168 + 144]) = pk(na.x, na.y);
        *(unsigned*)(&At[rl * 168 + 146]) = pk(na.z, na.w);
        unsigned* tailp = (unsigned*)(&At[rl * 168 + 148]);
        #pragma unroll
        for (int q = 0; q < 10; q++) tailp[q] = 0u;
    }
    __syncthreads();

    int wv = tid >> 6, lane = tid & 63, c = lane & 15, quad = lane >> 4;
    f32x4 acc[2][5] = {};
    #pragma unroll
    for (int kc = 0; kc < 5; kc++) {
        int k0 = kc * 32 + quad * 8;
        short8 a0 = *(const short8*)(&At[(wv * 32 + c) * 168 + k0]);
        short8 a1 = *(const short8*)(&At[(wv * 32 + 16 + c) * 168 + k0]);
        #pragma unroll
        for (int ct = 0; ct < 5; ct++) {
            short8 bf = *(const short8*)(&Wt[(ct * 16 + c) * 168 + k0]);
            acc[0][ct] = __builtin_amdgcn_mfma_f32_16x16x32_bf16(a0, bf, acc[0][ct], 0, 0, 0);
            acc[1][ct] = __builtin_amdgcn_mfma_f32_16x16x32_bf16(a1, bf, acc[1][ct], 0, 0, 0);
        }
    }
    size_t rbase = (size_t)blockIdx.x * 128 + wv * 32 + quad * 4;
    #pragma unroll
    for (int ct = 0; ct < 5; ct++) {
        int col = ct * 16 + c;
        float bias = (col < 72) ? bh1[col] : 0.f;
        float s = 0.f, q = 0.f;
        #pragma unroll
        for (int rt = 0; rt < 2; rt++) {
            float* op = z2 + (rbase + rt * 16) * 72 + col;
            #pragma unroll
            for (int r = 0; r < 4; r++) {
                float v = acc[rt][ct][r] + bias;
                if (col < 72) op[(size_t)r * 72] = v;
                s += v; q += v * v;
            }
        }
        s += __shfl_xor(s, 16); s += __shfl_xor(s, 32);
        q += __shfl_xor(q, 16); q += __shfl_xor(q, 32);
        if (lane < 16 && col < 72) { sred[wv][col] = s; sred[wv][72 + col] = q; }
    }
    __syncthreads();
    if (tid < 144)
        atomicAdd(&st[tid], sred[0][tid] + sred[1][tid] + sred[2][tid] + sred[3][tid]);
}

// ---------- node final: BN2+ReLU -> MFMA @Wh2 + bh2 + h ; x_out
__global__ __launch_bounds__(256) void k_node_final(
    const float* __restrict__ h, const float* __restrict__ x,
    const float* __restrict__ z2, const float* __restrict__ st2,
    const float* __restrict__ gh, const float* __restrict__ bh,
    const unsigned short* __restrict__ Wh2t, const float* __restrict__ bh2,
    const float* __restrict__ agg, const float* __restrict__ cnt,
    float* __restrict__ hout, float* __restrict__ xout)
{
    __shared__ unsigned short Zt[128 * 104];
    __shared__ unsigned short Wt[80 * 104];
    int tid = threadIdx.x;
    {
        const uint4* s = (const uint4*)Wh2t; uint4* d = (uint4*)Wt;
        for (int q = tid; q < 1040; q += 256) d[q] = s[q];
    }
    int rl = tid >> 1, half = tid & 1;
    size_t row = (size_t)blockIdx.x * 128 + rl;
    const float* mean = st2 + 144;
    const float* inv  = st2 + 216;
    const float4* zp = (const float4*)(z2 + row * 72) + half * 9;
    uint2* arow = (uint2*)(&Zt[rl * 104 + half * 36]);
    #pragma unroll
    for (int q = 0; q < 9; q++) {
        int k = half * 36 + q * 4;
        float4 v = zp[q];
        float a0 = fmaxf((v.x - mean[k  ]) * inv[k  ] * gh[k  ] + bh[k  ], 0.f);
        float a1 = fmaxf((v.y - mean[k+1]) * inv[k+1] * gh[k+1] + bh[k+1], 0.f);
        float a2 = fmaxf((v.z - mean[k+2]) * inv[k+2] * gh[k+2] + bh[k+2], 0.f);
        float a3 = fmaxf((v.w - mean[k+3]) * inv[k+3] * gh[k+3] + bh[k+3], 0.f);
        arow[q] = make_uint2(pk(a0, a1), pk(a2, a3));
    }
    uint2* prow = (uint2*)(&Zt[rl * 104]);
    #pragma unroll
    for (int q = 0; q < 4; q++) prow[18 + half * 4 + q] = make_uint2(0u, 0u);
    __syncthreads();

    int wv = tid >> 6, lane = tid & 63, c = lane & 15, quad = lane >> 4;
    f32x4 acc[2][5] = {};
    #pragma unroll
    for (int kc = 0; kc < 3; kc++) {
        int k0 = kc * 32 + quad * 8;
        short8 a0 = *(const short8*)(&Zt[(wv * 32 + c) * 104 + k0]);
        short8 a1 = *(const short8*)(&Zt[(wv * 32 + 16 + c) * 104 + k0]);
        #pragma unroll
        for (int ct = 0; ct < 5; ct++) {
            short8 bf = *(const short8*)(&Wt[(ct * 16 + c) * 104 + k0]);
            acc[0][ct] = __builtin_amdgcn_mfma_f32_16x16x32_bf16(a0, bf, acc[0][ct], 0, 0, 0);
            acc[1][ct] = __builtin_amdgcn_mfma_f32_16x16x32_bf16(a1, bf, acc[1][ct], 0, 0, 0);
        }
    }
    size_t rbase = (size_t)blockIdx.x * 128 + wv * 32 + quad * 4;
    #pragma unroll
    for (int rt = 0; rt < 2; rt++)
        #pragma unroll
        for (int ct = 0; ct < 5; ct++) {
            int col = ct * 16 + c;
            if (col < 72) {
                float bias = bh2[col];
                #pragma unroll
                for (int r = 0; r < 4; r++) {
                    size_t gr = (rbase + rt * 16 + r);
                    hout[gr * 72 + col] = h[gr * 72 + col] + acc[rt][ct][r] + bias;
                }
            }
        }
    if (tid < 128) {
        size_t nrow = (size_t)blockIdx.x * 128 + tid;
        float cn = fmaxf(cnt[nrow], 1.f);
        float4 ag = *(const float4*)(agg + nrow * 4);
        float4 xv = *(const float4*)(x + nrow * 4);
        ((float4*)xout)[nrow] = make_float4(xv.x + ag.x / cn, xv.y + ag.y / cn,
                                            xv.z + ag.z / cn, xv.w + ag.w / cn);
    }
}

extern "C" void kernel_launch(void* const* d_in, const int* in_sizes, int n_in,
                              void* d_out, int out_size, void* d_ws, size_t ws_size,
                              hipStream_t stream)
{
    const float* h   = (const float*)d_in[0];
    const float* x   = (const float*)d_in[1];
    const int*   ei  = (const int*)d_in[2];
    const int*   ej  = (const int*)d_in[3];
    const float* na  = (const float*)d_in[4];
    const float* We1 = (const float*)d_in[5];
    const float* g1  = (const float*)d_in[6];
    const float* b1  = (const float*)d_in[7];
    const float* We2 = (const float*)d_in[8];
    const float* be2 = (const float*)d_in[9];
    const float* Wm  = (const float*)d_in[10];
    const float* bm  = (const float*)d_in[11];
    const float* Wx1 = (const float*)d_in[12];
    const float* bx1 = (const float*)d_in[13];
    const float* Wx2 = (const float*)d_in[14];
    const float* Wh1 = (const float*)d_in[15];
    const float* bh1 = (const float*)d_in[16];
    const float* gh  = (const float*)d_in[17];
    const float* bhp = (const float*)d_in[18];
    const float* Wh2 = (const float*)d_in[19];
    const float* bh2 = (const float*)d_in[20];

    float* out  = (float*)d_out;
    float* hout = out;
    float* xout = out + XOUT_OFF;
    float* m    = out + M_OFF;
    float* ws   = (float*)d_ws;
    float* st1  = ws + ST1_OFF;
    float* st2  = ws + ST2_OFF;
    float* agg  = ws + AGG_OFF;
    float* cnt  = ws + CNT_OFF;
    float* magg = ws + MAGG_OFF;
    float* z2   = ws + Z2_OFF;
    unsigned short* wb = (unsigned short*)(ws + WB_OFF);
    // ab scratch overlays magg+z2 (consumed before they're written);
    // Wab^T overlays xout (written only by k_node_final at the very end)
    float* ab = ws + MAGG_OFF;
    unsigned short* wab = (unsigned short*)xout;

    hipMemsetAsync(d_ws, 0, (size_t)MAGG_OFF * sizeof(float), stream);
    k_prep<<<(PREP_TOTAL + 255) / 256, 256, 0, stream>>>(We1, We2, Wx1, Wh1, Wh2, wb, wab);
    k_ab<<<ROWS_N / 128, 256, 0, stream>>>(h, wab, ab);
    k_stats_lite<<<1024, dim3(72, 4), 0, stream>>>(ab, x, ei, ej, We1, st1);
    k_finalize1<<<1, 128, 0, stream>>>(st1, g1, b1, 1.0f / (float)ROWS_E);
    k_edge_fused<<<ROWS_E / 128, 256, 0, stream>>>(ab, x, ei, ej, We1, st1, be2, Wm, bm,
                                                   bx1, Wx2, wb + WE2T_OFF, wb + WX1T_OFF,
                                                   m, agg, cnt);
    hipMemsetAsync(magg, 0, (size_t)(ROWS_N * 72) * sizeof(float), stream);
    k_magg<<<1024, 256, 0, stream>>>(m, ei, magg);
    k_node_gemm1<<<ROWS_N / 128, 256, 0, stream>>>(h, na, magg, wb + WH1T_OFF, bh1, z2, st2);
    k_finalize<<<1, 128, 0, stream>>>(st2, 1.0f / (float)ROWS_N);
    k_node_final<<<ROWS_N / 128, 256, 0, stream>>>(h, x, z2, st2, gh, bhp,
                                                   wb + WH2T_OFF, bh2, agg, cnt, hout, xout);
}